// Round 18
// baseline (293.265 us; speedup 1.0000x reference)
//
#include <hip/hip_runtime.h>
#include <hip/hip_fp16.h>

#define B_    16
#define C_    256
#define HW_   4096
#define CHW_  1048576
#define N_    65536
#define K_    1024
#define FLT_BIG 3.402823466e38f
#define GAP_T  1.2e-4f   // ref fp32-quant floor 6.1e-5 + 6sigma fp16 score err ~3.1e-5 + key-pack 8e-6 + margin

typedef _Float16 half8 __attribute__((ext_vector_type(8)));
typedef float   float16 __attribute__((ext_vector_type(16)));

__device__ __forceinline__ unsigned umin_(unsigned a, unsigned b) { return a < b ? a : b; }
__device__ __forceinline__ unsigned umax_(unsigned a, unsigned b) { return a > b ? a : b; }

// ---------------------------------------------------------------------------
// Merged pre-pass (PASSED r17): szp + cbh + cbT + sc in ONE launch.
// Grid 5188 x 256: [0,4096)=szp, [4096,5120)=cbh, [5120,5184)=cbT,
// [5184,5188)=sc.  r18: block 0 thread 0 also zeroes count/lacc/done
// (stream-ordered before their consumers; re-runs on every graph replay)
// -> memset launch removed.
// ---------------------------------------------------------------------------
__global__ void pre_kernel(const float* __restrict__ z, const float* __restrict__ cb,
                           float* __restrict__ rp, unsigned short* __restrict__ cbh,
                           float* __restrict__ cbT, float* __restrict__ sc,
                           int* __restrict__ count, double* __restrict__ lacc,
                           int* __restrict__ done) {
    __shared__ float tile[64][65];
    int b = blockIdx.x;
    if (b == 0 && threadIdx.x == 0) {
        *count = 0;
        *lacc = 0.0;
        *done = 0;
    }
    if (b < 4096) {
        // s_z partial (PASSED r7/r15): thread owns ONE (h,j) chain, seq i-order
#pragma clang fp contract(off)
        int hj = b >> 8;                   // 0..15  (h = hj>>3, j = hj&7)
        int bx = b & 255;
        int n  = bx * 256 + threadIdx.x;
        int h = hj >> 3, j = hj & 7;
        const float* p = z + (size_t)(n >> 12) * CHW_ + (n & 4095)
                           + (size_t)(h * 128 + j) * HW_;
        float v = p[0];
        float r = v * v;
        for (int s = 1; s < 16; s++) {
            float u = p[(size_t)(s * 8) * HW_];
            r += u * u;
        }
        rp[(size_t)hj * N_ + n] = r;
    } else if (b < 5120) {
        // cbh: codebook -> fp16 (x1024 exact scale), A-fragment image
        int k = b - 4096, c = threadIdx.x;
        float v = cb[(size_t)k * C_ + c] * 1024.0f;
        __half hv = __float2half_rn(v);
        size_t F = ((size_t)(c >> 4) * 1024 + k) * 16 + ((c >> 3) & 1) * 8 + (c & 7);
        cbh[F] = __half_as_ushort(hv);
    } else if (b < 5184) {
        // cbT[c][k] = cb[k][c], LDS-tiled 64x64 (PASSED r15)
        int bb = b - 5120;
        int bx = bb & 15;                  // k-tile 0..15
        int by = bb >> 4;                  // c-tile 0..3
        int tc = threadIdx.x & 63, tr = threadIdx.x >> 6;
#pragma unroll
        for (int i = 0; i < 16; i++) {
            int k = tr + i * 4;
            tile[k][tc] = cb[(size_t)(bx * 64 + k) * C_ + by * 64 + tc];
        }
        __syncthreads();
#pragma unroll
        for (int i = 0; i < 16; i++) {
            int cc = tr + i * 4;
            cbT[(size_t)(by * 64 + cc) * K_ + bx * 64 + tc] = tile[tc][cc];
        }
    } else {
        // s_c[k] numpy pairwise order (PASSED r2/r4)
#pragma clang fp contract(off)
        int k = (b - 5184) * 256 + threadIdx.x;
        const float* p0 = cb + (size_t)k * C_;
        float blk[2];
        for (int h = 0; h < 2; h++) {
            const float* p = p0 + h * 128;
            float r[8];
#pragma unroll
            for (int j = 0; j < 8; j++) { float v = p[j]; r[j] = v * v; }
            for (int i = 8; i < 128; i += 8) {
#pragma unroll
                for (int j = 0; j < 8; j++) { float v = p[i + j]; r[j] += v * v; }
            }
            blk[h] = ((r[0] + r[1]) + (r[2] + r[3])) + ((r[4] + r[5]) + (r[6] + r[7]));
        }
        sc[k] = blk[0] + blk[1];
    }
}

// ---------------------------------------------------------------------------
// fp16 MFMA score kernel.  Block = 64 pixels, 256 thr (4 waves).
// (structure PASSED r6-r8/r15-r17; setprio T5 r8; depth-3 prefetch r16;
// flag+szc fused r17)
// NOTE: LDS deliberately 41984 B (3 blocks/CU).  All 40960-B (4 blocks/CU)
// variants failed idx verification 3-for-3 (r3/r4/r5) with identical
// arithmetic - do not retry without a mechanism.
// ---------------------------------------------------------------------------
__global__ __launch_bounds__(256, 4)
void score_kernel(const float* __restrict__ z, const unsigned short* __restrict__ cbh,
                  const float* __restrict__ sc, const float* __restrict__ rp,
                  int* __restrict__ fidx, float* __restrict__ out_idx,
                  int* __restrict__ list, int* __restrict__ count,
                  float* __restrict__ sz) {
    __shared__ __align__(16) int zw[64 * 132];   // 33792 B
    __shared__ float scs[1024];                  // 4 KB
    __shared__ float ex[4 * 64 * 4];             // 4 KB

    int t = threadIdx.x;
    int w = t >> 6, l = t & 63;
    int n0 = blockIdx.x * 64;

    for (int i = t; i < 1024; i += 256) scs[i] = sc[i] + 0.25f;

    {
        int px = l;
        const float* zp = z + (size_t)(n0 >> 12) * CHW_ + (n0 & 4095) + px;
        int key = (px >> 3) & 3;
#pragma unroll 4
        for (int i = 0; i < 32; i++) {
            int widx = w * 32 + i;
            int c0 = widx * 2;
            float v0 = zp[(size_t)c0 * HW_];
            float v1 = zp[(size_t)(c0 + 1) * HW_];
            unsigned pk = (unsigned)__half_as_ushort(__float2half_rn(v0))
                        | ((unsigned)__half_as_ushort(__float2half_rn(v1)) << 16);
            int c16 = widx >> 2, rem = widx & 3;
            zw[px * 132 + (((c16 ^ key) << 2) | rem)] = pk;
        }
    }
    __syncthreads();

    unsigned b1[2] = { 0xFFFFFFFFu, 0xFFFFFFFFu };
    unsigned b2[2] = { 0xFFFFFFFFu, 0xFFFFFFFFu };

    const unsigned short* ab = cbh + ((size_t)(w * 64 + (l & 31)) * 16 + (l >> 5) * 8);
    short rowmap = (short)((l >> 5) << 2);
    half8 pf[3][2];
#pragma unroll
    for (int i = 0; i < 3; i++) {
        const unsigned short* s = ab + (i & 15) * 16384 + (i >> 4) * 4096;
        pf[i][0] = *(const half8*)(s);
        pf[i][1] = *(const half8*)(s + 512);
    }

    int bkey = ((l & 31) >> 3) & 3;
    int prow0 = (l & 31) * 132;

#pragma unroll
    for (int chunk = 0; chunk < 4; chunk++) {
        float16 acc[2][2];
#pragma unroll
        for (int mt = 0; mt < 2; mt++)
#pragma unroll
            for (int nt = 0; nt < 2; nt++)
#pragma unroll
                for (int r = 0; r < 16; r++) acc[mt][nt][r] = 0.f;

#pragma unroll
        for (int kk = 0; kk < 16; kk++) {
            int step = chunk * 16 + kk;
            int buf = step % 3;
            half8 a0 = pf[buf][0], a1 = pf[buf][1];
            int ns = step + 3; if (ns > 63) ns = 63;
            {
                const unsigned short* s = ab + (ns & 15) * 16384 + (ns >> 4) * 4096;
                pf[buf][0] = *(const half8*)(s);
                pf[buf][1] = *(const half8*)(s + 512);
            }
            half8 bz[2];
#pragma unroll
            for (int nt = 0; nt < 2; nt++) {
                int c16 = kk * 2 + (l >> 5);
                int word = (nt * 32 * 132 + prow0) + ((c16 ^ bkey) << 2);
                bz[nt] = *(const half8*)((const char*)zw + (size_t)word * 4);
            }
            __builtin_amdgcn_s_setprio(1);
            acc[0][0] = __builtin_amdgcn_mfma_f32_32x32x16_f16(a0, bz[0], acc[0][0], 0, 0, 0);
            acc[0][1] = __builtin_amdgcn_mfma_f32_32x32x16_f16(a0, bz[1], acc[0][1], 0, 0, 0);
            acc[1][0] = __builtin_amdgcn_mfma_f32_32x32x16_f16(a1, bz[0], acc[1][0], 0, 0, 0);
            acc[1][1] = __builtin_amdgcn_mfma_f32_32x32x16_f16(a1, bz[1], acc[1][1], 0, 0, 0);
            __builtin_amdgcn_s_setprio(0);
        }

#pragma unroll
        for (int mt = 0; mt < 2; mt++)
#pragma unroll
            for (int r = 0; r < 16; r++) {
                int scode = chunk * 256 + w * 64 + mt * 32
                          + (r & 3) + ((r >> 2) << 3) + rowmap;
                float sv = scs[scode];
                unsigned emb = (unsigned)((chunk << 5) | (mt << 4) | r);
#pragma unroll
                for (int nt = 0; nt < 2; nt++) {
                    float s = fmaf(-0.001953125f, acc[mt][nt][r], sv);
                    unsigned key = (__float_as_uint(s) & 0xFFFFFF80u) | emb;
                    b2[nt] = umin_(b2[nt], umax_(b1[nt], key));
                    b1[nt] = umin_(b1[nt], key);
                }
            }
    }

#pragma unroll
    for (int nt = 0; nt < 2; nt++) {
        unsigned e1 = b1[nt] & 127u;
        float f1 = __uint_as_float(b1[nt] & 0xFFFFFF80u);
        float f2 = __uint_as_float(b2[nt] & 0xFFFFFF80u);
        int idx = (int)(e1 >> 5) * 256 + w * 64 + (int)((e1 >> 4) & 1) * 32
                + (int)(e1 & 3) + (int)(((e1 >> 2) & 3) << 3) + (int)rowmap;

        float of1 = __shfl_xor(f1, 32, 64);
        int   oi  = __shfl_xor(idx, 32, 64);
        float of2 = __shfl_xor(f2, 32, 64);
        if (of1 < f1 || (of1 == f1 && oi < idx)) {
            f2 = fminf(f1, of2); f1 = of1; idx = oi;
        } else {
            f2 = fminf(f2, of1);
        }

        if (l < 32) {
            int e = (w * 64 + nt * 32 + l) * 4;
            ex[e + 0] = f1;
            ex[e + 1] = f2;
            ((int*)ex)[e + 2] = idx;
        }
    }
    __syncthreads();
    if (t < 64) {
        float cb1 = FLT_BIG, cb2 = FLT_BIG; int cj1 = 0;
#pragma unroll
        for (int wv = 0; wv < 4; wv++) {
            int e = (wv * 64 + t) * 4;
            float nb1 = ex[e + 0];
            float nb2 = ex[e + 1];
            int   nj1 = ((int*)ex)[e + 2];
            if (nb1 < cb1 || (nb1 == cb1 && nj1 < cj1)) {
                cb2 = fminf(cb1, nb2); cb1 = nb1; cj1 = nj1;
            } else {
                cb2 = fminf(cb2, nb1);
            }
        }
        int n = n0 + t;
        // fused szc (r15/r16/r17-verified, exact pairwise tree)
        {
#pragma clang fp contract(off)
            float blk[2];
            for (int h = 0; h < 2; h++) {
                const float* bp = rp + (size_t)(h * 8) * N_ + n;
                float r0 = bp[0 * N_], r1 = bp[1 * N_], r2 = bp[2 * N_], r3 = bp[3 * N_];
                float r4 = bp[4 * N_], r5 = bp[5 * N_], r6 = bp[6 * N_], r7 = bp[7 * N_];
                blk[h] = ((r0 + r1) + (r2 + r3)) + ((r4 + r5) + (r6 + r7));
            }
            sz[n] = blk[0] + blk[1];
        }
        // fused flag: commit winner; compact near-ties
        fidx[n] = cj1;
        out_idx[n] = (float)cj1;
        if (cb2 - cb1 < GAP_T) {
            int pos = atomicAdd(count, 1);
            list[pos] = n;
        }
    }
}

// ---------------------------------------------------------------------------
// Exact refine (r8 P=1 VERBATIM - refine is CLOSED, at its L2 roofline:
// cnt~2400 x 1MB cbT sweep = 2.4GB / 72us ~ 33TB/s vs 34.5TB/s ceiling).
// Sharing structures all lost more to registers/latency than BW saved:
// r9 P=4 spill 126us; r11/r12/r13 P=2 scratch-pinned 275-278us;
// r14 LDS-tiled 111us.  Do not reopen.
// ---------------------------------------------------------------------------
__global__ void refine_kernel(const float* __restrict__ z, const float* __restrict__ cbT,
                              const float* __restrict__ sz, const float* __restrict__ sc,
                              const int* __restrict__ list, const int* __restrict__ count,
                              int* __restrict__ fidx, float* __restrict__ out_idx) {
    __shared__ double zd[4][256];
    int w = threadIdx.x >> 6, l = threadIdx.x & 63;
    int cnt = *count;
    if (cnt > 65536) cnt = 65536;
    for (int ii = blockIdx.x * 4 + w; ii < cnt; ii += 8192) {
        int n = list[ii];
        const float* zp = z + (size_t)(n >> 12) * CHW_ + (n & 4095);
#pragma unroll
        for (int j = 0; j < 4; j++)
            zd[w][l * 4 + j] = (double)zp[(size_t)(l * 4 + j) * HW_];
        asm volatile("s_waitcnt lgkmcnt(0)" ::: "memory");
        double acc[16];
#pragma unroll
        for (int a = 0; a < 16; a++) acc[a] = 0.0;
        for (int c = 0; c < 256; c++) {
            double zc = zd[w][c];
            const float* cp = cbT + (size_t)c * K_ + l * 4;
#pragma unroll
            for (int it = 0; it < 4; it++) {
                float4 cv = *(const float4*)(cp + it * 256);
                acc[it * 4 + 0] += zc * (double)cv.x;
                acc[it * 4 + 1] += zc * (double)cv.y;
                acc[it * 4 + 2] += zc * (double)cv.z;
                acc[it * 4 + 3] += zc * (double)cv.w;
            }
        }
        float szv = sz[n];
        float best = FLT_BIG; int bidx = K_;
#pragma unroll
        for (int it = 0; it < 4; it++)
#pragma unroll
            for (int s = 0; s < 4; s++) {
                int k = it * 256 + l * 4 + s;
                float dotf = (float)acc[it * 4 + s];
                float dq = (szv + sc[k]) - 2.0f * dotf;
                if (dq < best || (dq == best && k < bidx)) { best = dq; bidx = k; }
            }
#pragma unroll
        for (int off = 32; off > 0; off >>= 1) {
            float ob = __shfl_xor(best, off, 64);
            int   oj = __shfl_xor(bidx, off, 64);
            if (ob < best || (ob == best && oj < bidx)) { best = ob; bidx = oj; }
        }
        if (l == 0) { fidx[n] = bidx; out_idx[n] = (float)bidx; }
        asm volatile("s_waitcnt lgkmcnt(0)" ::: "memory");
    }
}

// ---------------------------------------------------------------------------
// Gather zq -> NCHW output + loss partials (float4 body PASSED r8/r15-r17).
// r18: loss fused via last-block pattern - each block atomicAdds its f64
// partial into lacc (device-scope f64 atomic), __threadfence, ticket;
// ticket 1023 reads the coherent sum (atomicAdd(lacc,0.0)) and writes
// out_loss.  Reassociation in f64 only (~1e-13).  loss launch + partials
// array removed.
// ---------------------------------------------------------------------------
__global__ void output_kernel(const float* __restrict__ z, const float* __restrict__ cb,
                              const int* __restrict__ fidx,
                              float* __restrict__ out0, double* __restrict__ lacc,
                              int* __restrict__ done, float* __restrict__ out_loss) {
    __shared__ int sidx[64];
    __shared__ double red[256];
    int t = threadIdx.x;
    int blk = blockIdx.x;
    int n0 = blk * 64;
    if (t < 64) sidx[t] = fidx[n0 + t];
    __syncthreads();
    int batch = n0 >> 12, s0 = n0 & 4095;
    const float* zbase = z + (size_t)batch * CHW_ + s0;
    float* obase = out0 + (size_t)batch * CHW_ + s0;
    int ig = (t & 15) * 4;
    int cg = (t >> 4) * 4;
    const float* r0 = cb + (size_t)sidx[ig + 0] * C_;
    const float* r1 = cb + (size_t)sidx[ig + 1] * C_;
    const float* r2 = cb + (size_t)sidx[ig + 2] * C_;
    const float* r3 = cb + (size_t)sidx[ig + 3] * C_;
    double sum = 0.0;
#pragma unroll
    for (int pass = 0; pass < 4; pass++) {
        int c0 = pass * 64 + cg;
        float4 q0 = *(const float4*)(r0 + c0);
        float4 q1 = *(const float4*)(r1 + c0);
        float4 q2 = *(const float4*)(r2 + c0);
        float4 q3 = *(const float4*)(r3 + c0);
        float a0[4] = { q0.x, q0.y, q0.z, q0.w };
        float a1[4] = { q1.x, q1.y, q1.z, q1.w };
        float a2[4] = { q2.x, q2.y, q2.z, q2.w };
        float a3[4] = { q3.x, q3.y, q3.z, q3.w };
#pragma unroll
        for (int j = 0; j < 4; j++) {
            size_t off = (size_t)(c0 + j) * HW_ + ig;
            float4 zv = *(const float4*)(zbase + off);
            float4 qq;
            qq.x = a0[j]; qq.y = a1[j]; qq.z = a2[j]; qq.w = a3[j];
            *(float4*)(obase + off) = qq;
            float d0 = qq.x - zv.x, d1 = qq.y - zv.y;
            float d2 = qq.z - zv.z, d3 = qq.w - zv.w;
            sum += (double)d0 * (double)d0;
            sum += (double)d1 * (double)d1;
            sum += (double)d2 * (double)d2;
            sum += (double)d3 * (double)d3;
        }
    }
    red[t] = sum;
    __syncthreads();
    for (int s = 128; s > 0; s >>= 1) {
        if (t < s) red[t] += red[t + s];
        __syncthreads();
    }
    if (t == 0) {
        atomicAdd(lacc, red[0]);
        __threadfence();
        int ticket = atomicAdd(done, 1);
        if (ticket == 1023) {
            double total = atomicAdd(lacc, 0.0);   // device-coherent read
            *out_loss = (float)(0.75 * total / 16777216.0);
        }
    }
}

// ---------------------------------------------------------------------------
extern "C" void kernel_launch(void* const* d_in, const int* in_sizes, int n_in,
                              void* d_out, int out_size, void* d_ws, size_t ws_size,
                              hipStream_t stream) {
    const float* z  = (const float*)d_in[0];
    const float* cb = (const float*)d_in[1];

    float* out0     = (float*)d_out;
    float* out_idx  = out0 + (size_t)16777216;
    float* out_loss = out0 + (size_t)16842752;

    char* w = (char*)d_ws;
    double* lacc = (double*)w;                           //       0 .. 8
    int*    done = (int*)  (w + 8);                      //       8 .. 12
    int*    count= (int*)  (w + 12);                     //      12 .. 16
    float*  sc   = (float*)(w + 8192);                   //    8192 .. 12288
    float*  sz   = (float*)(w + 12288);                  //   12288 .. 274432
    int*    fidx = (int*)  (w + 274432);                 //  274432 .. 536576 (256 KB)
    int*    list = (int*)  (w + 536832);                 //  536832 .. 798976 (256 KB)
    unsigned short* cbh = (unsigned short*)(w + 798976); //  798976 .. 1323264 (512 KB)
    float*  cbT  = (float*)(w + 1323264);                // 1323264 .. 2371840 (1 MB)
    float*  rp   = (float*)(w + 2371840);                // 2371840 .. 6566144 (4 MB)

    pre_kernel   <<<5188, 256, 0, stream>>>(z, cb, rp, cbh, cbT, sc, count, lacc, done);
    score_kernel <<<1024, 256, 0, stream>>>(z, cbh, sc, rp, fidx, out_idx, list, count, sz);
    refine_kernel<<<2048, 256, 0, stream>>>(z, cbT, sz, sc, list, count, fidx, out_idx);
    output_kernel<<<1024, 256, 0, stream>>>(z, cb, fidx, out0, lacc, done, out_loss);
}

// Round 19
// 265.257 us; speedup vs baseline: 1.1056x; 1.1056x over previous
//
#include <hip/hip_runtime.h>
#include <hip/hip_fp16.h>

#define B_    16
#define C_    256
#define HW_   4096
#define CHW_  1048576
#define N_    65536
#define K_    1024
#define FLT_BIG 3.402823466e38f
#define GAP_T  1.2e-4f   // ref fp32-quant floor 6.1e-5 + 6sigma fp16 score err ~3.1e-5 + key-pack 8e-6 + margin

typedef _Float16 half8 __attribute__((ext_vector_type(8)));
typedef float   float16 __attribute__((ext_vector_type(16)));

__device__ __forceinline__ unsigned umin_(unsigned a, unsigned b) { return a < b ? a : b; }
__device__ __forceinline__ unsigned umax_(unsigned a, unsigned b) { return a > b ? a : b; }

// ---------------------------------------------------------------------------
// Merged pre-pass (PASSED r17 at 264.1us - REVERTED to this config after
// r18's loss-fusion regression: 1024 per-block __threadfence L2 flushes
// cost +29us > the ~8us launch savings.  Do not re-fuse loss.
// Grid 5188 x 256: [0,4096)=szp, [4096,5120)=cbh, [5120,5184)=cbT,
// [5184,5188)=sc.
// ---------------------------------------------------------------------------
__global__ void pre_kernel(const float* __restrict__ z, const float* __restrict__ cb,
                           float* __restrict__ rp, unsigned short* __restrict__ cbh,
                           float* __restrict__ cbT, float* __restrict__ sc) {
    __shared__ float tile[64][65];
    int b = blockIdx.x;
    if (b < 4096) {
        // s_z partial (PASSED r7/r15): thread owns ONE (h,j) chain, seq i-order
#pragma clang fp contract(off)
        int hj = b >> 8;                   // 0..15  (h = hj>>3, j = hj&7)
        int bx = b & 255;
        int n  = bx * 256 + threadIdx.x;
        int h = hj >> 3, j = hj & 7;
        const float* p = z + (size_t)(n >> 12) * CHW_ + (n & 4095)
                           + (size_t)(h * 128 + j) * HW_;
        float v = p[0];
        float r = v * v;
        for (int s = 1; s < 16; s++) {
            float u = p[(size_t)(s * 8) * HW_];
            r += u * u;
        }
        rp[(size_t)hj * N_ + n] = r;
    } else if (b < 5120) {
        // cbh: codebook -> fp16 (x1024 exact scale), A-fragment image
        int k = b - 4096, c = threadIdx.x;
        float v = cb[(size_t)k * C_ + c] * 1024.0f;
        __half hv = __float2half_rn(v);
        size_t F = ((size_t)(c >> 4) * 1024 + k) * 16 + ((c >> 3) & 1) * 8 + (c & 7);
        cbh[F] = __half_as_ushort(hv);
    } else if (b < 5184) {
        // cbT[c][k] = cb[k][c], LDS-tiled 64x64 (PASSED r15)
        int bb = b - 5120;
        int bx = bb & 15;                  // k-tile 0..15
        int by = bb >> 4;                  // c-tile 0..3
        int tc = threadIdx.x & 63, tr = threadIdx.x >> 6;
#pragma unroll
        for (int i = 0; i < 16; i++) {
            int k = tr + i * 4;
            tile[k][tc] = cb[(size_t)(bx * 64 + k) * C_ + by * 64 + tc];
        }
        __syncthreads();
#pragma unroll
        for (int i = 0; i < 16; i++) {
            int cc = tr + i * 4;
            cbT[(size_t)(by * 64 + cc) * K_ + bx * 64 + tc] = tile[tc][cc];
        }
    } else {
        // s_c[k] numpy pairwise order (PASSED r2/r4)
#pragma clang fp contract(off)
        int k = (b - 5184) * 256 + threadIdx.x;
        const float* p0 = cb + (size_t)k * C_;
        float blk[2];
        for (int h = 0; h < 2; h++) {
            const float* p = p0 + h * 128;
            float r[8];
#pragma unroll
            for (int j = 0; j < 8; j++) { float v = p[j]; r[j] = v * v; }
            for (int i = 8; i < 128; i += 8) {
#pragma unroll
                for (int j = 0; j < 8; j++) { float v = p[i + j]; r[j] += v * v; }
            }
            blk[h] = ((r[0] + r[1]) + (r[2] + r[3])) + ((r[4] + r[5]) + (r[6] + r[7]));
        }
        sc[k] = blk[0] + blk[1];
    }
}

// ---------------------------------------------------------------------------
// fp16 MFMA score kernel.  Block = 64 pixels, 256 thr (4 waves).
// (structure PASSED r6-r8/r15-r17; setprio T5 r8; depth-3 prefetch r16;
// flag+szc fused r17)
// NOTE: LDS deliberately 41984 B (3 blocks/CU).  All 40960-B (4 blocks/CU)
// variants failed idx verification 3-for-3 (r3/r4/r5) with identical
// arithmetic - do not retry without a mechanism.
// ---------------------------------------------------------------------------
__global__ __launch_bounds__(256, 4)
void score_kernel(const float* __restrict__ z, const unsigned short* __restrict__ cbh,
                  const float* __restrict__ sc, const float* __restrict__ rp,
                  int* __restrict__ fidx, float* __restrict__ out_idx,
                  int* __restrict__ list, int* __restrict__ count,
                  float* __restrict__ sz) {
    __shared__ __align__(16) int zw[64 * 132];   // 33792 B
    __shared__ float scs[1024];                  // 4 KB
    __shared__ float ex[4 * 64 * 4];             // 4 KB

    int t = threadIdx.x;
    int w = t >> 6, l = t & 63;
    int n0 = blockIdx.x * 64;

    for (int i = t; i < 1024; i += 256) scs[i] = sc[i] + 0.25f;

    {
        int px = l;
        const float* zp = z + (size_t)(n0 >> 12) * CHW_ + (n0 & 4095) + px;
        int key = (px >> 3) & 3;
#pragma unroll 4
        for (int i = 0; i < 32; i++) {
            int widx = w * 32 + i;
            int c0 = widx * 2;
            float v0 = zp[(size_t)c0 * HW_];
            float v1 = zp[(size_t)(c0 + 1) * HW_];
            unsigned pk = (unsigned)__half_as_ushort(__float2half_rn(v0))
                        | ((unsigned)__half_as_ushort(__float2half_rn(v1)) << 16);
            int c16 = widx >> 2, rem = widx & 3;
            zw[px * 132 + (((c16 ^ key) << 2) | rem)] = pk;
        }
    }
    __syncthreads();

    unsigned b1[2] = { 0xFFFFFFFFu, 0xFFFFFFFFu };
    unsigned b2[2] = { 0xFFFFFFFFu, 0xFFFFFFFFu };

    const unsigned short* ab = cbh + ((size_t)(w * 64 + (l & 31)) * 16 + (l >> 5) * 8);
    short rowmap = (short)((l >> 5) << 2);
    half8 pf[3][2];
#pragma unroll
    for (int i = 0; i < 3; i++) {
        const unsigned short* s = ab + (i & 15) * 16384 + (i >> 4) * 4096;
        pf[i][0] = *(const half8*)(s);
        pf[i][1] = *(const half8*)(s + 512);
    }

    int bkey = ((l & 31) >> 3) & 3;
    int prow0 = (l & 31) * 132;

#pragma unroll
    for (int chunk = 0; chunk < 4; chunk++) {
        float16 acc[2][2];
#pragma unroll
        for (int mt = 0; mt < 2; mt++)
#pragma unroll
            for (int nt = 0; nt < 2; nt++)
#pragma unroll
                for (int r = 0; r < 16; r++) acc[mt][nt][r] = 0.f;

#pragma unroll
        for (int kk = 0; kk < 16; kk++) {
            int step = chunk * 16 + kk;
            int buf = step % 3;
            half8 a0 = pf[buf][0], a1 = pf[buf][1];
            int ns = step + 3; if (ns > 63) ns = 63;
            {
                const unsigned short* s = ab + (ns & 15) * 16384 + (ns >> 4) * 4096;
                pf[buf][0] = *(const half8*)(s);
                pf[buf][1] = *(const half8*)(s + 512);
            }
            half8 bz[2];
#pragma unroll
            for (int nt = 0; nt < 2; nt++) {
                int c16 = kk * 2 + (l >> 5);
                int word = (nt * 32 * 132 + prow0) + ((c16 ^ bkey) << 2);
                bz[nt] = *(const half8*)((const char*)zw + (size_t)word * 4);
            }
            __builtin_amdgcn_s_setprio(1);
            acc[0][0] = __builtin_amdgcn_mfma_f32_32x32x16_f16(a0, bz[0], acc[0][0], 0, 0, 0);
            acc[0][1] = __builtin_amdgcn_mfma_f32_32x32x16_f16(a0, bz[1], acc[0][1], 0, 0, 0);
            acc[1][0] = __builtin_amdgcn_mfma_f32_32x32x16_f16(a1, bz[0], acc[1][0], 0, 0, 0);
            acc[1][1] = __builtin_amdgcn_mfma_f32_32x32x16_f16(a1, bz[1], acc[1][1], 0, 0, 0);
            __builtin_amdgcn_s_setprio(0);
        }

#pragma unroll
        for (int mt = 0; mt < 2; mt++)
#pragma unroll
            for (int r = 0; r < 16; r++) {
                int scode = chunk * 256 + w * 64 + mt * 32
                          + (r & 3) + ((r >> 2) << 3) + rowmap;
                float sv = scs[scode];
                unsigned emb = (unsigned)((chunk << 5) | (mt << 4) | r);
#pragma unroll
                for (int nt = 0; nt < 2; nt++) {
                    float s = fmaf(-0.001953125f, acc[mt][nt][r], sv);
                    unsigned key = (__float_as_uint(s) & 0xFFFFFF80u) | emb;
                    b2[nt] = umin_(b2[nt], umax_(b1[nt], key));
                    b1[nt] = umin_(b1[nt], key);
                }
            }
    }

#pragma unroll
    for (int nt = 0; nt < 2; nt++) {
        unsigned e1 = b1[nt] & 127u;
        float f1 = __uint_as_float(b1[nt] & 0xFFFFFF80u);
        float f2 = __uint_as_float(b2[nt] & 0xFFFFFF80u);
        int idx = (int)(e1 >> 5) * 256 + w * 64 + (int)((e1 >> 4) & 1) * 32
                + (int)(e1 & 3) + (int)(((e1 >> 2) & 3) << 3) + (int)rowmap;

        float of1 = __shfl_xor(f1, 32, 64);
        int   oi  = __shfl_xor(idx, 32, 64);
        float of2 = __shfl_xor(f2, 32, 64);
        if (of1 < f1 || (of1 == f1 && oi < idx)) {
            f2 = fminf(f1, of2); f1 = of1; idx = oi;
        } else {
            f2 = fminf(f2, of1);
        }

        if (l < 32) {
            int e = (w * 64 + nt * 32 + l) * 4;
            ex[e + 0] = f1;
            ex[e + 1] = f2;
            ((int*)ex)[e + 2] = idx;
        }
    }
    __syncthreads();
    if (t < 64) {
        float cb1 = FLT_BIG, cb2 = FLT_BIG; int cj1 = 0;
#pragma unroll
        for (int wv = 0; wv < 4; wv++) {
            int e = (wv * 64 + t) * 4;
            float nb1 = ex[e + 0];
            float nb2 = ex[e + 1];
            int   nj1 = ((int*)ex)[e + 2];
            if (nb1 < cb1 || (nb1 == cb1 && nj1 < cj1)) {
                cb2 = fminf(cb1, nb2); cb1 = nb1; cj1 = nj1;
            } else {
                cb2 = fminf(cb2, nb1);
            }
        }
        int n = n0 + t;
        // fused szc (r15/r16/r17-verified, exact pairwise tree)
        {
#pragma clang fp contract(off)
            float blk[2];
            for (int h = 0; h < 2; h++) {
                const float* bp = rp + (size_t)(h * 8) * N_ + n;
                float r0 = bp[0 * N_], r1 = bp[1 * N_], r2 = bp[2 * N_], r3 = bp[3 * N_];
                float r4 = bp[4 * N_], r5 = bp[5 * N_], r6 = bp[6 * N_], r7 = bp[7 * N_];
                blk[h] = ((r0 + r1) + (r2 + r3)) + ((r4 + r5) + (r6 + r7));
            }
            sz[n] = blk[0] + blk[1];
        }
        // fused flag: commit winner; compact near-ties
        fidx[n] = cj1;
        out_idx[n] = (float)cj1;
        if (cb2 - cb1 < GAP_T) {
            int pos = atomicAdd(count, 1);
            list[pos] = n;
        }
    }
}

// ---------------------------------------------------------------------------
// Exact refine (r8 P=1 VERBATIM - refine is CLOSED, at its L2 roofline:
// cnt~2400 x 1MB cbT sweep = 2.4GB / 72us ~ 33TB/s vs 34.5TB/s ceiling).
// Sharing structures all lost more to registers/latency than BW saved:
// r9 P=4 spill 126us; r11/r12/r13 P=2 scratch-pinned 275-278us;
// r14 LDS-tiled 111us.  Do not reopen.
// ---------------------------------------------------------------------------
__global__ void refine_kernel(const float* __restrict__ z, const float* __restrict__ cbT,
                              const float* __restrict__ sz, const float* __restrict__ sc,
                              const int* __restrict__ list, const int* __restrict__ count,
                              int* __restrict__ fidx, float* __restrict__ out_idx) {
    __shared__ double zd[4][256];
    int w = threadIdx.x >> 6, l = threadIdx.x & 63;
    int cnt = *count;
    if (cnt > 65536) cnt = 65536;
    for (int ii = blockIdx.x * 4 + w; ii < cnt; ii += 8192) {
        int n = list[ii];
        const float* zp = z + (size_t)(n >> 12) * CHW_ + (n & 4095);
#pragma unroll
        for (int j = 0; j < 4; j++)
            zd[w][l * 4 + j] = (double)zp[(size_t)(l * 4 + j) * HW_];
        asm volatile("s_waitcnt lgkmcnt(0)" ::: "memory");
        double acc[16];
#pragma unroll
        for (int a = 0; a < 16; a++) acc[a] = 0.0;
        for (int c = 0; c < 256; c++) {
            double zc = zd[w][c];
            const float* cp = cbT + (size_t)c * K_ + l * 4;
#pragma unroll
            for (int it = 0; it < 4; it++) {
                float4 cv = *(const float4*)(cp + it * 256);
                acc[it * 4 + 0] += zc * (double)cv.x;
                acc[it * 4 + 1] += zc * (double)cv.y;
                acc[it * 4 + 2] += zc * (double)cv.z;
                acc[it * 4 + 3] += zc * (double)cv.w;
            }
        }
        float szv = sz[n];
        float best = FLT_BIG; int bidx = K_;
#pragma unroll
        for (int it = 0; it < 4; it++)
#pragma unroll
            for (int s = 0; s < 4; s++) {
                int k = it * 256 + l * 4 + s;
                float dotf = (float)acc[it * 4 + s];
                float dq = (szv + sc[k]) - 2.0f * dotf;
                if (dq < best || (dq == best && k < bidx)) { best = dq; bidx = k; }
            }
#pragma unroll
        for (int off = 32; off > 0; off >>= 1) {
            float ob = __shfl_xor(best, off, 64);
            int   oj = __shfl_xor(bidx, off, 64);
            if (ob < best || (ob == best && oj < bidx)) { best = ob; bidx = oj; }
        }
        if (l == 0) { fidx[n] = bidx; out_idx[n] = (float)bidx; }
        asm volatile("s_waitcnt lgkmcnt(0)" ::: "memory");
    }
}

// ---------------------------------------------------------------------------
// Gather zq -> NCHW output + loss partials (float4 version, PASSED r8-r17)
// ---------------------------------------------------------------------------
__global__ void output_kernel(const float* __restrict__ z, const float* __restrict__ cb,
                              const int* __restrict__ fidx,
                              float* __restrict__ out0, double* __restrict__ partials) {
    __shared__ int sidx[64];
    __shared__ double red[256];
    int t = threadIdx.x;
    int blk = blockIdx.x;
    int n0 = blk * 64;
    if (t < 64) sidx[t] = fidx[n0 + t];
    __syncthreads();
    int batch = n0 >> 12, s0 = n0 & 4095;
    const float* zbase = z + (size_t)batch * CHW_ + s0;
    float* obase = out0 + (size_t)batch * CHW_ + s0;
    int ig = (t & 15) * 4;
    int cg = (t >> 4) * 4;
    const float* r0 = cb + (size_t)sidx[ig + 0] * C_;
    const float* r1 = cb + (size_t)sidx[ig + 1] * C_;
    const float* r2 = cb + (size_t)sidx[ig + 2] * C_;
    const float* r3 = cb + (size_t)sidx[ig + 3] * C_;
    double sum = 0.0;
#pragma unroll
    for (int pass = 0; pass < 4; pass++) {
        int c0 = pass * 64 + cg;
        float4 q0 = *(const float4*)(r0 + c0);
        float4 q1 = *(const float4*)(r1 + c0);
        float4 q2 = *(const float4*)(r2 + c0);
        float4 q3 = *(const float4*)(r3 + c0);
        float a0[4] = { q0.x, q0.y, q0.z, q0.w };
        float a1[4] = { q1.x, q1.y, q1.z, q1.w };
        float a2[4] = { q2.x, q2.y, q2.z, q2.w };
        float a3[4] = { q3.x, q3.y, q3.z, q3.w };
#pragma unroll
        for (int j = 0; j < 4; j++) {
            size_t off = (size_t)(c0 + j) * HW_ + ig;
            float4 zv = *(const float4*)(zbase + off);
            float4 qq;
            qq.x = a0[j]; qq.y = a1[j]; qq.z = a2[j]; qq.w = a3[j];
            *(float4*)(obase + off) = qq;
            float d0 = qq.x - zv.x, d1 = qq.y - zv.y;
            float d2 = qq.z - zv.z, d3 = qq.w - zv.w;
            sum += (double)d0 * (double)d0;
            sum += (double)d1 * (double)d1;
            sum += (double)d2 * (double)d2;
            sum += (double)d3 * (double)d3;
        }
    }
    red[t] = sum;
    __syncthreads();
    for (int s = 128; s > 0; s >>= 1) {
        if (t < s) red[t] += red[t + s];
        __syncthreads();
    }
    if (t == 0) partials[blk] = red[0];
}

__global__ void loss_kernel(const double* __restrict__ partials, float* __restrict__ out_loss) {
    __shared__ double red[256];
    int t = threadIdx.x;
    double s = 0.0;
    for (int r = t; r < 1024; r += 256) s += partials[r];
    red[t] = s;
    __syncthreads();
    for (int k = 128; k > 0; k >>= 1) {
        if (t < k) red[t] += red[t + k];
        __syncthreads();
    }
    if (t == 0) *out_loss = (float)(0.75 * red[0] / 16777216.0);
}

// ---------------------------------------------------------------------------
extern "C" void kernel_launch(void* const* d_in, const int* in_sizes, int n_in,
                              void* d_out, int out_size, void* d_ws, size_t ws_size,
                              hipStream_t stream) {
    const float* z  = (const float*)d_in[0];
    const float* cb = (const float*)d_in[1];

    float* out0     = (float*)d_out;
    float* out_idx  = out0 + (size_t)16777216;
    float* out_loss = out0 + (size_t)16842752;

    char* w = (char*)d_ws;
    double* partials = (double*)w;                       //       0 .. 8192
    float*  sc   = (float*)(w + 8192);                   //    8192 .. 12288
    float*  sz   = (float*)(w + 12288);                  //   12288 .. 274432
    int*    fidx = (int*)  (w + 274432);                 //  274432 .. 536576 (256 KB)
    int*    count= (int*)  (w + 536576);                 //  536576 .. 536580
    int*    list = (int*)  (w + 536832);                 //  536832 .. 798976 (256 KB)
    unsigned short* cbh = (unsigned short*)(w + 798976); //  798976 .. 1323264 (512 KB)
    float*  cbT  = (float*)(w + 1323264);                // 1323264 .. 2371840 (1 MB)
    float*  rp   = (float*)(w + 2371840);                // 2371840 .. 6566144 (4 MB)

    hipMemsetAsync(count, 0, 4, stream);
    pre_kernel   <<<5188, 256, 0, stream>>>(z, cb, rp, cbh, cbT, sc);
    score_kernel <<<1024, 256, 0, stream>>>(z, cbh, sc, rp, fidx, out_idx, list, count, sz);
    refine_kernel<<<2048, 256, 0, stream>>>(z, cbT, sz, sc, list, count, fidx, out_idx);
    output_kernel<<<1024, 256, 0, stream>>>(z, cb, fidx, out0, partials);
    loss_kernel  <<<1,    256, 0, stream>>>(partials, out_loss);
}